// Round 4
// baseline (339.915 us; speedup 1.0000x reference)
//
#include <hip/hip_runtime.h>
#include <math.h>

#define PI2F 6.28318530717958647692f

__host__ __device__ constexpr int br6(int p) {
    return ((p & 1) << 5) | ((p & 2) << 3) | ((p & 4) << 1) |
           ((p & 8) >> 1) | ((p & 16) >> 3) | ((p & 32) >> 5);
}
__host__ __device__ constexpr int brN(int v, int bits) {
    int r = 0;
    for (int i = 0; i < bits; ++i) r |= ((v >> i) & 1) << (bits - 1 - i);
    return r;
}

// 64-pt naive-cas butterfly twiddles: cas(2*pi*k/s)
__device__ static constexpr float CAS8T[4] = {1.f, 1.41421356f, 1.f, 0.f};
__device__ static constexpr float CAS16T[8] = {
    1.f, 1.30656296f, 1.41421356f, 1.30656296f, 1.f, 0.54119610f, 0.f, -0.54119610f};
__device__ static constexpr float CAS32T[16] = {
    1.f, 1.17587560f, 1.30656296f, 1.38703985f, 1.41421356f, 1.38703985f,
    1.30656296f, 1.17587560f, 1.f, 0.78569496f, 0.54119610f, 0.27589938f,
    0.f, -0.27589938f, -0.54119610f, -0.78569496f};
__device__ static constexpr float CAS64T[32] = {
    1.f, 1.09320187f, 1.17587560f, 1.24722502f, 1.30656296f, 1.35331800f,
    1.38703985f, 1.40740373f, 1.41421356f, 1.40740373f, 1.38703985f,
    1.35331800f, 1.30656296f, 1.24722502f, 1.17587560f, 1.09320187f,
    1.f, 0.89716759f, 0.78569496f, 0.66665566f, 0.54119610f, 0.41052452f,
    0.27589938f, 0.13861717f, 0.f, -0.13861717f, -0.27589938f, -0.41052452f,
    -0.54119610f, -0.66665566f, -0.78569496f, -0.89716759f};

// K1: weight transform, coalesced read -> LDS transpose -> coalesced write.
// Extra block (x==128) generates casT (synthesis twiddle table for fht_inv).
__global__ __launch_bounds__(256) void wtrans_cast(const float* __restrict__ w,
                                                   float* __restrict__ wp,
                                                   float* __restrict__ wm,
                                                   float* __restrict__ casT) {
    const int tid = threadIdx.x;
    if (blockIdx.x == 128) {
        if (blockIdx.y != 0) return;
#pragma unroll
        for (int base = 0; base < 4096; base += 256) {
            const int idx = base + tid;
            if (idx < 4032) {
                const int j = idx >> 6, r = idx & 63;
                int l, u;
                if (j == 0) { l = 5; u = 0; }
                else if (j < 3) { l = 4; u = j - 1; }
                else if (j < 7) { l = 3; u = j - 3; }
                else if (j < 15) { l = 2; u = j - 7; }
                else if (j < 31) { l = 1; u = j - 15; }
                else { l = 0; u = j - 31; }
                float s, c;
                sincosf(PI2F * (float)(r + 64 * u) / (float)(4096 >> l), &s, &c);
                casT[j * 64 + r] = c + s;
            }
        }
        return;
    }
    __shared__ float W[64 * 65];   // W[o_local][m], stride 65 -> conflict-free both phases
    const int i = blockIdx.x;      // in-channel
    const int oh = blockIdx.y;     // o half (0..1)
    const float* src = w + (size_t)i * 8192 + oh * 4096;
#pragma unroll
    for (int it = 0; it < 4; ++it) {
        const int k = it * 1024 + tid * 4;       // coalesced float4 over (o_local, m)
        const float4 v = *(const float4*)(src + k);
        const int ol = k >> 6;
        const int ml = k & 63;
        W[ol * 65 + ml + 0] = v.x;
        W[ol * 65 + ml + 1] = v.y;
        W[ol * 65 + ml + 2] = v.z;
        W[ol * 65 + ml + 3] = v.w;
    }
    __syncthreads();
    const int mh = tid >> 6;       // wave id 0..3
    const int ol = tid & 63;       // lane = o_local -> coalesced stores
    const int o = oh * 64 + ol;
#pragma unroll
    for (int ml = 0; ml < 16; ++ml) {
        const int m = mh * 16 + ml;
        const int mp = (64 - m) & 63;
        const float a = W[ol * 65 + m];
        const float b = W[ol * 65 + mp];
        wp[((size_t)m * 128 + i) * 128 + o] = 0.5f * (a + b);
        wm[((size_t)m * 128 + i) * 128 + o] = 0.5f * (a - b);
    }
}

// Analysis: xh_t[r][row] = sum_c G[r,c] * y_c[r].
__global__ __launch_bounds__(64) void fht_fwd(const float* __restrict__ x,
                                              float* __restrict__ xh_t) {
    __shared__ __align__(16) float Y[64 * 68];   // [c][m], row stride 68 floats (272B)
    const int lane = threadIdx.x;

    float a6[6];
#pragma unroll
    for (int l = 0; l < 6; ++l) {
        float s, c;
        sincosf(PI2F * (float)lane / (float)(4096 >> l), &s, &c);
        a6[l] = c + s;
    }

    const int row0 = blockIdx.x * 2;
    float accs[2];
#pragma unroll 1
    for (int rr = 0; rr < 2; ++rr) {
        const float* xr = x + (size_t)(row0 + rr) * 4096 + lane;
        float v[64];
#pragma unroll
        for (int p = 0; p < 64; ++p) v[p] = xr[64 * br6(p)];

        // 64-pt naive-cas DIT butterfly (input bit-reversed in t)
#pragma unroll
        for (int b = 0; b < 64; b += 2) {
            float t0 = v[b], t1 = v[b + 1];
            v[b] = t0 + t1; v[b + 1] = t0 - t1;
        }
#pragma unroll
        for (int b = 0; b < 64; b += 4)
#pragma unroll
            for (int k = 0; k < 2; ++k) {
                float t0 = v[b + k], t1 = v[b + k + 2];
                v[b + k] = t0 + t1; v[b + k + 2] = t0 - t1;
            }
#pragma unroll
        for (int b = 0; b < 64; b += 8)
#pragma unroll
            for (int k = 0; k < 4; ++k) {
                float w = CAS8T[k];
                float t0 = v[b + k], t1 = v[b + k + 4];
                v[b + k] = fmaf(w, t1, t0); v[b + k + 4] = fmaf(-w, t1, t0);
            }
#pragma unroll
        for (int b = 0; b < 64; b += 16)
#pragma unroll
            for (int k = 0; k < 8; ++k) {
                float w = CAS16T[k];
                float t0 = v[b + k], t1 = v[b + k + 8];
                v[b + k] = fmaf(w, t1, t0); v[b + k + 8] = fmaf(-w, t1, t0);
            }
#pragma unroll
        for (int b = 0; b < 64; b += 32)
#pragma unroll
            for (int k = 0; k < 16; ++k) {
                float w = CAS32T[k];
                float t0 = v[b + k], t1 = v[b + k + 16];
                v[b + k] = fmaf(w, t1, t0); v[b + k + 16] = fmaf(-w, t1, t0);
            }
#pragma unroll
        for (int k = 0; k < 32; ++k) {
            float w = CAS64T[k];
            float t0 = v[k], t1 = v[k + 32];
            v[k] = fmaf(w, t1, t0); v[k + 32] = fmaf(-w, t1, t0);
        }

        // transpose via LDS: thread c writes its 64 outputs m-contiguous (16x b128)
        __syncthreads();
#pragma unroll
        for (int m4 = 0; m4 < 16; ++m4)
            *(float4*)&Y[lane * 68 + 4 * m4] =
                make_float4(v[4 * m4], v[4 * m4 + 1], v[4 * m4 + 2], v[4 * m4 + 3]);
        __syncthreads();
        // fold: v[c] = y_c[lane]; then 6-level pairwise fold with a6
#pragma unroll
        for (int c = 0; c < 64; ++c) v[c] = Y[c * 68 + lane];
#pragma unroll
        for (int l = 0; l < 6; ++l) {
            const int st = 1 << l;
#pragma unroll
            for (int k = 0; k < 64; k += 2 * st)
                v[k] = fmaf(a6[l], v[k + st], v[k]);
        }
        accs[rr] = v[0];
    }
    *(float2*)(xh_t + (size_t)lane * 8192 + row0) = make_float2(accs[0], accs[1]);
}

// Mode-mix GEMM: grid(64 m, 8 bt) -> same-m blocks land on the same XCD.
__global__ __launch_bounds__(256) void passB(const float* __restrict__ xh_t,
                                             const float* __restrict__ wp,
                                             const float* __restrict__ wm,
                                             float* __restrict__ mixed_t) {
    __shared__ float Us[8][132];     // [batch_local][i]
    __shared__ float Uns[8][132];
    const int tid = threadIdx.x;
    const int m = blockIdx.x;
    const int bt = blockIdx.y;       // batch tile (8 batches)
    const int mp = (64 - m) & 63;
    {
        const int bl = tid >> 5;             // 0..7
        const int i0 = (tid & 31) * 4;       // 0..124
        const float4 vu = *(const float4*)(xh_t + (size_t)m  * 8192 + bt * 1024 + tid * 4);
        const float4 vn = *(const float4*)(xh_t + (size_t)mp * 8192 + bt * 1024 + tid * 4);
        *(float4*)&Us[bl][i0] = vu;
        *(float4*)&Uns[bl][i0] = vn;
    }
    __syncthreads();
    const int b = tid >> 5;          // 0..7 batch_local
    const int o0 = (tid & 31) * 4;   // 4 out-channels per thread
    float acc[4];
#pragma unroll
    for (int j = 0; j < 4; ++j) acc[j] = 0.0f;
#pragma unroll 4
    for (int i = 0; i < 128; ++i) {
        float p[4], q[4];
        *(float4*)&p[0] = *(const float4*)(wp + ((size_t)m * 128 + i) * 128 + o0);
        *(float4*)&q[0] = *(const float4*)(wm + ((size_t)m * 128 + i) * 128 + o0);
        const float u = Us[b][i];
        const float un = Uns[b][i];
#pragma unroll
        for (int j = 0; j < 4; ++j) acc[j] += u * p[j] + un * q[j];
    }
    float* dst = mixed_t + (size_t)m * 8192 + (bt * 8 + b) * 128 + o0;
    *(float4*)dst = make_float4(acc[0], acc[1], acc[2], acc[3]);
}

// Synthesis: butterfly in registers; direct strided stores (coalesced 256B/instr).
__global__ __launch_bounds__(64) void fht_inv(const float* __restrict__ mixed_t,
                                              const float* __restrict__ casT,
                                              float* __restrict__ out) {
    __shared__ __align__(16) float S[64];
    const int lane = threadIdx.x;
    float K[63];
#pragma unroll
    for (int j = 0; j < 63; ++j) K[j] = casT[j * 64 + lane];

    const int row0 = blockIdx.x * 4;
    float4 mv4 = *(const float4*)(mixed_t + (size_t)lane * 8192 + row0);
    mv4.x *= (1.0f / 4096.0f); mv4.y *= (1.0f / 4096.0f);
    mv4.z *= (1.0f / 4096.0f); mv4.w *= (1.0f / 4096.0f);
    float mvs[4] = {mv4.x, mv4.y, mv4.z, mv4.w};

#pragma unroll 1
    for (int rr = 0; rr < 4; ++rr) {
        const int row = row0 + rr;
        __syncthreads();
        S[lane] = mvs[rr];
        __syncthreads();
        float e[64];
#pragma unroll
        for (int m4 = 0; m4 < 16; ++m4) {
            const float4 q = *(const float4*)&S[4 * m4];   // LDS broadcast
            e[4 * m4 + 0] = q.x; e[4 * m4 + 1] = q.y;
            e[4 * m4 + 2] = q.z; e[4 * m4 + 3] = q.w;
        }
        // level 5 (m bit5, K[0])
#pragma unroll
        for (int mp = 0; mp < 32; ++mp) {
            float w = K[0];
            float t0 = e[mp], t1 = e[mp + 32];
            e[mp] = fmaf(w, t1, t0); e[mp + 32] = fmaf(-w, t1, t0);
        }
        // level 4
#pragma unroll
        for (int hi = 0; hi < 2; ++hi)
#pragma unroll
            for (int mp = 0; mp < 16; ++mp) {
                float w = K[1 + brN(hi, 1)];
                int i0 = hi * 32 + mp;
                float t0 = e[i0], t1 = e[i0 + 16];
                e[i0] = fmaf(w, t1, t0); e[i0 + 16] = fmaf(-w, t1, t0);
            }
        // level 3
#pragma unroll
        for (int hi = 0; hi < 4; ++hi)
#pragma unroll
            for (int mp = 0; mp < 8; ++mp) {
                float w = K[3 + brN(hi, 2)];
                int i0 = hi * 16 + mp;
                float t0 = e[i0], t1 = e[i0 + 8];
                e[i0] = fmaf(w, t1, t0); e[i0 + 8] = fmaf(-w, t1, t0);
            }
        // level 2
#pragma unroll
        for (int hi = 0; hi < 8; ++hi)
#pragma unroll
            for (int mp = 0; mp < 4; ++mp) {
                float w = K[7 + brN(hi, 3)];
                int i0 = hi * 8 + mp;
                float t0 = e[i0], t1 = e[i0 + 4];
                e[i0] = fmaf(w, t1, t0); e[i0 + 4] = fmaf(-w, t1, t0);
            }
        // level 1
#pragma unroll
        for (int hi = 0; hi < 16; ++hi)
#pragma unroll
            for (int mp = 0; mp < 2; ++mp) {
                float w = K[15 + brN(hi, 4)];
                int i0 = hi * 4 + mp;
                float t0 = e[i0], t1 = e[i0 + 2];
                e[i0] = fmaf(w, t1, t0); e[i0 + 2] = fmaf(-w, t1, t0);
            }
        // level 0
#pragma unroll
        for (int hi = 0; hi < 32; ++hi) {
            float w = K[31 + brN(hi, 5)];
            int i0 = hi * 2;
            float t0 = e[i0], t1 = e[i0 + 1];
            e[i0] = fmaf(w, t1, t0); e[i0 + 1] = fmaf(-w, t1, t0);
        }
        float* outr = out + (size_t)row * 4096 + lane;
#pragma unroll
        for (int t = 0; t < 64; ++t) outr[64 * t] = e[br6(t)];
    }
}

// R4 PROBE: the full chain is idempotent (no atomics/accumulation), so launching
// it twice yields bit-identical output. dur_us(R4) - dur_us(R3) = true GPU cost
// of one chain; separates kernel time from fixed harness overhead.
extern "C" void kernel_launch(void* const* d_in, const int* in_sizes, int n_in,
                              void* d_out, int out_size, void* d_ws, size_t ws_size,
                              hipStream_t stream) {
    const float* x = (const float*)d_in[0];   // (64,128,4096)
    const float* w = (const float*)d_in[1];   // (128,128,64)
    float* out = (float*)d_out;               // (64,128,4096)
    float* wsf = (float*)d_ws;

    float* casT    = wsf + 512;        // 4032 floats
    float* xh_t    = wsf + 8192;       // [64][8192]  2 MB
    float* wp      = wsf + 532480;     // [64][128][128] 4 MB
    float* wm      = wsf + 1581056;    // 4 MB
    float* mixed_t = wsf + 2629632;    // [64][8192]  2 MB

    for (int rep = 0; rep < 2; ++rep) {
        wtrans_cast<<<dim3(129, 2), dim3(256), 0, stream>>>(w, wp, wm, casT);
        fht_fwd<<<dim3(4096), dim3(64), 0, stream>>>(x, xh_t);
        passB<<<dim3(64, 8), dim3(256), 0, stream>>>(xh_t, wp, wm, mixed_t);
        fht_inv<<<dim3(2048), dim3(64), 0, stream>>>(mixed_t, casT, out);
    }
}

// Round 5
// 265.703 us; speedup vs baseline: 1.2793x; 1.2793x over previous
//
#include <hip/hip_runtime.h>
#include <math.h>

#define PI2F 6.28318530717958647692f

__host__ __device__ constexpr int br6(int p) {
    return ((p & 1) << 5) | ((p & 2) << 3) | ((p & 4) << 1) |
           ((p & 8) >> 1) | ((p & 16) >> 3) | ((p & 32) >> 5);
}
__host__ __device__ constexpr int brN(int v, int bits) {
    int r = 0;
    for (int i = 0; i < bits; ++i) r |= ((v >> i) & 1) << (bits - 1 - i);
    return r;
}

// 64-pt naive-cas butterfly twiddles: cas(2*pi*k/s)
__device__ static constexpr float CAS8T[4] = {1.f, 1.41421356f, 1.f, 0.f};
__device__ static constexpr float CAS16T[8] = {
    1.f, 1.30656296f, 1.41421356f, 1.30656296f, 1.f, 0.54119610f, 0.f, -0.54119610f};
__device__ static constexpr float CAS32T[16] = {
    1.f, 1.17587560f, 1.30656296f, 1.38703985f, 1.41421356f, 1.38703985f,
    1.30656296f, 1.17587560f, 1.f, 0.78569496f, 0.54119610f, 0.27589938f,
    0.f, -0.27589938f, -0.54119610f, -0.78569496f};
__device__ static constexpr float CAS64T[32] = {
    1.f, 1.09320187f, 1.17587560f, 1.24722502f, 1.30656296f, 1.35331800f,
    1.38703985f, 1.40740373f, 1.41421356f, 1.40740373f, 1.38703985f,
    1.35331800f, 1.30656296f, 1.24722502f, 1.17587560f, 1.09320187f,
    1.f, 0.89716759f, 0.78569496f, 0.66665566f, 0.54119610f, 0.41052452f,
    0.27589938f, 0.13861717f, 0.f, -0.13861717f, -0.27589938f, -0.41052452f,
    -0.54119610f, -0.66665566f, -0.78569496f, -0.89716759f};

// K1: weight transform, coalesced read -> LDS transpose -> coalesced write.
// Extra block (x==128) generates casT (synthesis twiddle table for fht_inv).
__global__ __launch_bounds__(256) void wtrans_cast(const float* __restrict__ w,
                                                   float* __restrict__ wp,
                                                   float* __restrict__ wm,
                                                   float* __restrict__ casT) {
    const int tid = threadIdx.x;
    if (blockIdx.x == 128) {
        if (blockIdx.y != 0) return;
#pragma unroll
        for (int base = 0; base < 4096; base += 256) {
            const int idx = base + tid;
            if (idx < 4032) {
                const int j = idx >> 6, r = idx & 63;
                int l, u;
                if (j == 0) { l = 5; u = 0; }
                else if (j < 3) { l = 4; u = j - 1; }
                else if (j < 7) { l = 3; u = j - 3; }
                else if (j < 15) { l = 2; u = j - 7; }
                else if (j < 31) { l = 1; u = j - 15; }
                else { l = 0; u = j - 31; }
                float s, c;
                sincosf(PI2F * (float)(r + 64 * u) / (float)(4096 >> l), &s, &c);
                casT[j * 64 + r] = c + s;
            }
        }
        return;
    }
    __shared__ float W[64 * 65];   // W[o_local][m], stride 65 -> conflict-free both phases
    const int i = blockIdx.x;      // in-channel
    const int oh = blockIdx.y;     // o half (0..1)
    const float* src = w + (size_t)i * 8192 + oh * 4096;
#pragma unroll
    for (int it = 0; it < 4; ++it) {
        const int k = it * 1024 + tid * 4;       // coalesced float4 over (o_local, m)
        const float4 v = *(const float4*)(src + k);
        const int ol = k >> 6;
        const int ml = k & 63;
        W[ol * 65 + ml + 0] = v.x;
        W[ol * 65 + ml + 1] = v.y;
        W[ol * 65 + ml + 2] = v.z;
        W[ol * 65 + ml + 3] = v.w;
    }
    __syncthreads();
    const int mh = tid >> 6;       // wave id 0..3
    const int ol = tid & 63;       // lane = o_local -> coalesced stores
    const int o = oh * 64 + ol;
#pragma unroll
    for (int ml = 0; ml < 16; ++ml) {
        const int m = mh * 16 + ml;
        const int mp = (64 - m) & 63;
        const float a = W[ol * 65 + m];
        const float b = W[ol * 65 + mp];
        wp[((size_t)m * 128 + i) * 128 + o] = 0.5f * (a + b);
        wm[((size_t)m * 128 + i) * 128 + o] = 0.5f * (a - b);
    }
}

// Analysis: xh_t[r][row] = sum_c G[r,c] * y_c[r].
// Direct coalesced bit-rev loads (256B/instr); transpose [c][m] stride-68 with
// b128 writes; final reduce = 6-level multiplicative fold (63 fma, depth 6, no G table).
__global__ __launch_bounds__(64) void fht_fwd(const float* __restrict__ x,
                                              float* __restrict__ xh_t) {
    __shared__ __align__(16) float Y[64 * 68];   // [c][m], row stride 68 floats (272B)
    const int lane = threadIdx.x;

    float a6[6];
#pragma unroll
    for (int l = 0; l < 6; ++l) {
        float s, c;
        sincosf(PI2F * (float)lane / (float)(4096 >> l), &s, &c);
        a6[l] = c + s;
    }

    const int row0 = blockIdx.x * 2;
    float accs[2];
#pragma unroll 1
    for (int rr = 0; rr < 2; ++rr) {
        const float* xr = x + (size_t)(row0 + rr) * 4096 + lane;
        float v[64];
#pragma unroll
        for (int p = 0; p < 64; ++p) v[p] = xr[64 * br6(p)];

        // 64-pt naive-cas DIT butterfly (input bit-reversed in t)
#pragma unroll
        for (int b = 0; b < 64; b += 2) {
            float t0 = v[b], t1 = v[b + 1];
            v[b] = t0 + t1; v[b + 1] = t0 - t1;
        }
#pragma unroll
        for (int b = 0; b < 64; b += 4)
#pragma unroll
            for (int k = 0; k < 2; ++k) {
                float t0 = v[b + k], t1 = v[b + k + 2];
                v[b + k] = t0 + t1; v[b + k + 2] = t0 - t1;
            }
#pragma unroll
        for (int b = 0; b < 64; b += 8)
#pragma unroll
            for (int k = 0; k < 4; ++k) {
                float w = CAS8T[k];
                float t0 = v[b + k], t1 = v[b + k + 4];
                v[b + k] = fmaf(w, t1, t0); v[b + k + 4] = fmaf(-w, t1, t0);
            }
#pragma unroll
        for (int b = 0; b < 64; b += 16)
#pragma unroll
            for (int k = 0; k < 8; ++k) {
                float w = CAS16T[k];
                float t0 = v[b + k], t1 = v[b + k + 8];
                v[b + k] = fmaf(w, t1, t0); v[b + k + 8] = fmaf(-w, t1, t0);
            }
#pragma unroll
        for (int b = 0; b < 64; b += 32)
#pragma unroll
            for (int k = 0; k < 16; ++k) {
                float w = CAS32T[k];
                float t0 = v[b + k], t1 = v[b + k + 16];
                v[b + k] = fmaf(w, t1, t0); v[b + k + 16] = fmaf(-w, t1, t0);
            }
#pragma unroll
        for (int k = 0; k < 32; ++k) {
            float w = CAS64T[k];
            float t0 = v[k], t1 = v[k + 32];
            v[k] = fmaf(w, t1, t0); v[k + 32] = fmaf(-w, t1, t0);
        }

        // transpose via LDS: thread c writes its 64 outputs m-contiguous (16x b128,
        // conflict-free: quad index 17c+j bijective mod 8)
        __syncthreads();
#pragma unroll
        for (int m4 = 0; m4 < 16; ++m4)
            *(float4*)&Y[lane * 68 + 4 * m4] =
                make_float4(v[4 * m4], v[4 * m4 + 1], v[4 * m4 + 2], v[4 * m4 + 3]);
        __syncthreads();
        // fold: v[c] = y_c[lane]; then 6-level pairwise fold with a6 (Σ_c Π a6^{c_l} y_c)
#pragma unroll
        for (int c = 0; c < 64; ++c) v[c] = Y[c * 68 + lane];
#pragma unroll
        for (int l = 0; l < 6; ++l) {
            const int st = 1 << l;
#pragma unroll
            for (int k = 0; k < 64; k += 2 * st)
                v[k] = fmaf(a6[l], v[k + st], v[k]);
        }
        accs[rr] = v[0];
    }
    *(float2*)(xh_t + (size_t)lane * 8192 + row0) = make_float2(accs[0], accs[1]);
}

// Mode-mix GEMM: grid(64 m, 8 bt) -> all 8 blocks sharing an m-slice land on the
// SAME XCD (ids differ by 64 ≡ 0 mod 8) -> wp/wm slice fetched once per XCD.
__global__ __launch_bounds__(256) void passB(const float* __restrict__ xh_t,
                                             const float* __restrict__ wp,
                                             const float* __restrict__ wm,
                                             float* __restrict__ mixed_t) {
    __shared__ float Us[8][132];     // [batch_local][i]
    __shared__ float Uns[8][132];
    const int tid = threadIdx.x;
    const int m = blockIdx.x;
    const int bt = blockIdx.y;       // batch tile (8 batches)
    const int mp = (64 - m) & 63;
    {
        const int bl = tid >> 5;             // 0..7
        const int i0 = (tid & 31) * 4;       // 0..124
        const float4 vu = *(const float4*)(xh_t + (size_t)m  * 8192 + bt * 1024 + tid * 4);
        const float4 vn = *(const float4*)(xh_t + (size_t)mp * 8192 + bt * 1024 + tid * 4);
        *(float4*)&Us[bl][i0] = vu;
        *(float4*)&Uns[bl][i0] = vn;
    }
    __syncthreads();
    const int b = tid >> 5;          // 0..7 batch_local
    const int o0 = (tid & 31) * 4;   // 4 out-channels per thread
    float acc[4];
#pragma unroll
    for (int j = 0; j < 4; ++j) acc[j] = 0.0f;
#pragma unroll 4
    for (int i = 0; i < 128; ++i) {
        float p[4], q[4];
        *(float4*)&p[0] = *(const float4*)(wp + ((size_t)m * 128 + i) * 128 + o0);
        *(float4*)&q[0] = *(const float4*)(wm + ((size_t)m * 128 + i) * 128 + o0);
        const float u = Us[b][i];
        const float un = Uns[b][i];
#pragma unroll
        for (int j = 0; j < 4; ++j) acc[j] += u * p[j] + un * q[j];
    }
    float* dst = mixed_t + (size_t)m * 8192 + (bt * 8 + b) * 128 + o0;
    *(float4*)dst = make_float4(acc[0], acc[1], acc[2], acc[3]);
}

// Synthesis: butterfly in registers; direct strided stores (coalesced 256B/instr);
// no LDS staging -> near-zero LDS, VGPR-capped occupancy.
__global__ __launch_bounds__(64) void fht_inv(const float* __restrict__ mixed_t,
                                              const float* __restrict__ casT,
                                              float* __restrict__ out) {
    __shared__ __align__(16) float S[64];
    const int lane = threadIdx.x;
    float K[63];
#pragma unroll
    for (int j = 0; j < 63; ++j) K[j] = casT[j * 64 + lane];

    const int row0 = blockIdx.x * 4;
    float4 mv4 = *(const float4*)(mixed_t + (size_t)lane * 8192 + row0);
    mv4.x *= (1.0f / 4096.0f); mv4.y *= (1.0f / 4096.0f);
    mv4.z *= (1.0f / 4096.0f); mv4.w *= (1.0f / 4096.0f);
    float mvs[4] = {mv4.x, mv4.y, mv4.z, mv4.w};

#pragma unroll 1
    for (int rr = 0; rr < 4; ++rr) {
        const int row = row0 + rr;
        __syncthreads();
        S[lane] = mvs[rr];
        __syncthreads();
        float e[64];
#pragma unroll
        for (int m4 = 0; m4 < 16; ++m4) {
            const float4 q = *(const float4*)&S[4 * m4];   // LDS broadcast
            e[4 * m4 + 0] = q.x; e[4 * m4 + 1] = q.y;
            e[4 * m4 + 2] = q.z; e[4 * m4 + 3] = q.w;
        }
        // level 5 (m bit5, K[0])
#pragma unroll
        for (int mp = 0; mp < 32; ++mp) {
            float w = K[0];
            float t0 = e[mp], t1 = e[mp + 32];
            e[mp] = fmaf(w, t1, t0); e[mp + 32] = fmaf(-w, t1, t0);
        }
        // level 4
#pragma unroll
        for (int hi = 0; hi < 2; ++hi)
#pragma unroll
            for (int mp = 0; mp < 16; ++mp) {
                float w = K[1 + brN(hi, 1)];
                int i0 = hi * 32 + mp;
                float t0 = e[i0], t1 = e[i0 + 16];
                e[i0] = fmaf(w, t1, t0); e[i0 + 16] = fmaf(-w, t1, t0);
            }
        // level 3
#pragma unroll
        for (int hi = 0; hi < 4; ++hi)
#pragma unroll
            for (int mp = 0; mp < 8; ++mp) {
                float w = K[3 + brN(hi, 2)];
                int i0 = hi * 16 + mp;
                float t0 = e[i0], t1 = e[i0 + 8];
                e[i0] = fmaf(w, t1, t0); e[i0 + 8] = fmaf(-w, t1, t0);
            }
        // level 2
#pragma unroll
        for (int hi = 0; hi < 8; ++hi)
#pragma unroll
            for (int mp = 0; mp < 4; ++mp) {
                float w = K[7 + brN(hi, 3)];
                int i0 = hi * 8 + mp;
                float t0 = e[i0], t1 = e[i0 + 4];
                e[i0] = fmaf(w, t1, t0); e[i0 + 4] = fmaf(-w, t1, t0);
            }
        // level 1
#pragma unroll
        for (int hi = 0; hi < 16; ++hi)
#pragma unroll
            for (int mp = 0; mp < 2; ++mp) {
                float w = K[15 + brN(hi, 4)];
                int i0 = hi * 4 + mp;
                float t0 = e[i0], t1 = e[i0 + 2];
                e[i0] = fmaf(w, t1, t0); e[i0 + 2] = fmaf(-w, t1, t0);
            }
        // level 0
#pragma unroll
        for (int hi = 0; hi < 32; ++hi) {
            float w = K[31 + brN(hi, 5)];
            int i0 = hi * 2;
            float t0 = e[i0], t1 = e[i0 + 1];
            e[i0] = fmaf(w, t1, t0); e[i0 + 1] = fmaf(-w, t1, t0);
        }
        float* outr = out + (size_t)row * 4096 + lane;
#pragma unroll
        for (int t = 0; t < 64; ++t) outr[64 * t] = e[br6(t)];
    }
}

// Final configuration (reverted from the R4 2x-chain probe).
// Probe evidence: one chain = 73.4 us on-GPU; measured window carries ~193 us
// fixed harness overhead. Chain is within ~1.5x of its 278 MB compulsory-traffic
// floor (~48 us); remaining gap is latency-bound 1-wave FHT blocks with
// demonstrated +-2 us/round movability.
extern "C" void kernel_launch(void* const* d_in, const int* in_sizes, int n_in,
                              void* d_out, int out_size, void* d_ws, size_t ws_size,
                              hipStream_t stream) {
    const float* x = (const float*)d_in[0];   // (64,128,4096)
    const float* w = (const float*)d_in[1];   // (128,128,64)
    float* out = (float*)d_out;               // (64,128,4096)
    float* wsf = (float*)d_ws;

    float* casT    = wsf + 512;        // 4032 floats
    float* xh_t    = wsf + 8192;       // [64][8192]  2 MB
    float* wp      = wsf + 532480;     // [64][128][128] 4 MB
    float* wm      = wsf + 1581056;    // 4 MB
    float* mixed_t = wsf + 2629632;    // [64][8192]  2 MB

    wtrans_cast<<<dim3(129, 2), dim3(256), 0, stream>>>(w, wp, wm, casT);
    fht_fwd<<<dim3(4096), dim3(64), 0, stream>>>(x, xh_t);
    passB<<<dim3(64, 8), dim3(256), 0, stream>>>(xh_t, wp, wm, mixed_t);
    fht_inv<<<dim3(2048), dim3(64), 0, stream>>>(mixed_t, casT, out);
}